// Round 1
// baseline (3559.741 us; speedup 1.0000x reference)
//
#include <hip/hip_runtime.h>
#include <hip/hip_bf16.h>

// ---------------------------------------------------------------------------
// GIN (3 layers, eps=0) + global mean pool + FC.
// Inputs: x[N,9] f32, edge_index[2,E] int, batch[N] int (sorted),
//         W1[64,9] b1[64], W2[128,64] b2[128], W3[64,128] b3[64],
//         Wfc[11,64] bfc[11].  Output: [G,11] f32, G = out_size/11.
//
// Algebraic restructuring: Lin(h + agg) = Lin(h) + Lin(agg) (linearity), so
// aggregate in whichever space (input/output of the Linear) is narrower:
//   L1: scatter x (9-dim), then Linear 9->64 + relu
//   L2: scatter h1 (64-dim), then Linear 64->128 + relu
//   L3: t3 = h2 @ W3^T first (128->64), scatter t3 (64-dim), then +b3, relu
// ---------------------------------------------------------------------------

__global__ __launch_bounds__(256) void scatter9_kernel(
    const float* __restrict__ x, const int* __restrict__ src,
    const int* __restrict__ dst, float* __restrict__ agg, int E)
{
    int e = blockIdx.x * 256 + threadIdx.x;
    if (e >= E) return;
    int s = src[e], d = dst[e];
    const float* xs = &x[(size_t)s * 9];
    float* ad = &agg[(size_t)d * 9];
    #pragma unroll
    for (int k = 0; k < 9; ++k) atomicAdd(&ad[k], xs[k]);
}

// D floats per row, 4 per thread (D % 4 == 0, D/4 power of two)
template<int D>
__global__ __launch_bounds__(256) void scatter_kernel(
    const float* __restrict__ h, const int* __restrict__ src,
    const int* __restrict__ dst, float* __restrict__ agg, int E)
{
    constexpr int C = D / 4;
    int t = blockIdx.x * 256 + threadIdx.x;
    int e = t / C;
    if (e >= E) return;
    int c = (t % C) * 4;
    int s = src[e], d = dst[e];
    float4 v = *(const float4*)&h[(size_t)s * D + c];
    float* p = &agg[(size_t)d * D + c];
    atomicAdd(p + 0, v.x);
    atomicAdd(p + 1, v.y);
    atomicAdd(p + 2, v.z);
    atomicAdd(p + 3, v.w);
}

// h1[n,o] = relu((x[n]+agg1[n]) . W1[o] + b1[o]);  one thread per (n,o)
__global__ __launch_bounds__(256) void node1_kernel(
    const float* __restrict__ x, const float* __restrict__ agg1,
    const float* __restrict__ W1, const float* __restrict__ b1,
    float* __restrict__ h1, int N)
{
    __shared__ float Wl[576];
    __shared__ float bl[64];
    if (threadIdx.x < 64) bl[threadIdx.x] = b1[threadIdx.x];
    for (int i = threadIdx.x; i < 576; i += 256) Wl[i] = W1[i];
    __syncthreads();
    int t = blockIdx.x * 256 + threadIdx.x;
    int n = t >> 6, o = t & 63;
    if (n >= N) return;
    float s = bl[o];
    const float* xr = &x[(size_t)n * 9];
    const float* ar = &agg1[(size_t)n * 9];
    const float* wr = &Wl[o * 9];
    #pragma unroll
    for (int k = 0; k < 9; ++k) s += (xr[k] + ar[k]) * wr[k];
    h1[(size_t)n * 64 + o] = fmaxf(s, 0.f);
}

// Y[n,:OUT] = (A[n] + Badd[n]) @ W^T (+bias) (relu optional)
// W is [OUT,IN] row-major. Block: NB nodes x OUT outs, 256 threads.
template<int IN, int OUT, int NB, bool RELU>
__global__ __launch_bounds__(256) void linear_kernel(
    const float* __restrict__ A, const float* __restrict__ Badd,
    const float* __restrict__ W, const float* __restrict__ bias,
    float* __restrict__ Y, int N)
{
    constexpr int INP = IN + 4;            // pad: keeps float4 align, breaks bank stride
    constexpr int OT  = OUT / 4;           // threads along out-dim
    constexpr int NPT = (NB * OT) / 256;   // nodes per thread
    __shared__ float Wl[IN][OUT];          // W transposed: [k][o]
    __shared__ float S[NB][INP];           // staged (A+Badd) rows
    int tid = threadIdx.x;
    // stage W transposed (strided global reads; W <=32KB, L1-resident)
    for (int i = tid; i < IN * OUT; i += 256) {
        int k = i / OUT, o = i % OUT;
        Wl[k][o] = W[o * IN + k];
    }
    int n0 = blockIdx.x * NB;
    for (int i = tid; i < NB * IN / 4; i += 256) {
        int idx = i * 4;
        int node = idx / IN, k = idx % IN;
        int gn = n0 + node;
        float4 v = make_float4(0.f, 0.f, 0.f, 0.f);
        if (gn < N) {
            v = *(const float4*)&A[(size_t)gn * IN + k];
            if (Badd) {
                float4 b4 = *(const float4*)&Badd[(size_t)gn * IN + k];
                v.x += b4.x; v.y += b4.y; v.z += b4.z; v.w += b4.w;
            }
        }
        *(float4*)&S[node][k] = v;
    }
    __syncthreads();
    int ot = (tid % OT) * 4;
    int nt = (tid / OT) * NPT;
    float acc[NPT][4];
    #pragma unroll
    for (int i = 0; i < NPT; ++i)
        acc[i][0] = acc[i][1] = acc[i][2] = acc[i][3] = 0.f;
    #pragma unroll 4
    for (int k = 0; k < IN; ++k) {
        float4 w = *(const float4*)&Wl[k][ot];
        #pragma unroll
        for (int i = 0; i < NPT; ++i) {
            float a = S[nt + i][k];
            acc[i][0] += a * w.x; acc[i][1] += a * w.y;
            acc[i][2] += a * w.z; acc[i][3] += a * w.w;
        }
    }
    float4 bv = make_float4(0.f, 0.f, 0.f, 0.f);
    if (bias) bv = *(const float4*)&bias[ot];
    #pragma unroll
    for (int i = 0; i < NPT; ++i) {
        int gn = n0 + nt + i;
        if (gn < N) {
            float4 r;
            r.x = acc[i][0] + bv.x; r.y = acc[i][1] + bv.y;
            r.z = acc[i][2] + bv.z; r.w = acc[i][3] + bv.w;
            if (RELU) {
                r.x = fmaxf(r.x, 0.f); r.y = fmaxf(r.y, 0.f);
                r.z = fmaxf(r.z, 0.f); r.w = fmaxf(r.w, 0.f);
            }
            *(float4*)&Y[(size_t)gn * OUT + ot] = r;
        }
    }
}

// h3 = relu(t3 + agg3 + b3), in place over t3.  One float4 per thread.
__global__ __launch_bounds__(256) void node3_kernel(
    float* __restrict__ t3, const float* __restrict__ agg3,
    const float* __restrict__ b3, int total4)
{
    int i = blockIdx.x * 256 + threadIdx.x;
    if (i >= total4) return;
    float4 a = ((const float4*)t3)[i];
    float4 g = ((const float4*)agg3)[i];
    float4 bv = ((const float4*)b3)[i & 15];   // 64 floats per row = 16 float4s
    float4 r;
    r.x = fmaxf(a.x + g.x + bv.x, 0.f);
    r.y = fmaxf(a.y + g.y + bv.y, 0.f);
    r.z = fmaxf(a.z + g.z + bv.z, 0.f);
    r.w = fmaxf(a.w + g.w + bv.w, 0.f);
    ((float4*)t3)[i] = r;
}

__device__ inline int lower_bound_i(const int* a, int n, int v) {
    int lo = 0, hi = n;
    while (lo < hi) {
        int mid = (lo + hi) >> 1;
        if (a[mid] < v) lo = mid + 1; else hi = mid;
    }
    return lo;
}

// One block (64 threads = 1 wave) per graph: mean-pool its node range
// (batch is sorted), then FC 64->11.
__global__ __launch_bounds__(64) void pool_fc_kernel(
    const float* __restrict__ h3, const int* __restrict__ batch,
    const float* __restrict__ Wfc, const float* __restrict__ bfc,
    float* __restrict__ out, int N)
{
    int g = blockIdx.x;
    int lane = threadIdx.x;
    int lo = lower_bound_i(batch, N, g);
    int hi = lower_bound_i(batch, N, g + 1);
    float sum = 0.f;
    for (int i = lo; i < hi; ++i) sum += h3[(size_t)i * 64 + lane];
    float cnt = (float)((hi - lo) > 0 ? (hi - lo) : 1);
    __shared__ float P[64];
    P[lane] = sum / cnt;
    __syncthreads();
    if (lane < 11) {
        float s = bfc[lane];
        const float* wr = &Wfc[lane * 64];
        #pragma unroll 8
        for (int k = 0; k < 64; ++k) s += P[k] * wr[k];
        out[g * 11 + lane] = s;
    }
}

extern "C" void kernel_launch(void* const* d_in, const int* in_sizes, int n_in,
                              void* d_out, int out_size, void* d_ws, size_t ws_size,
                              hipStream_t stream) {
    const float* x    = (const float*)d_in[0];
    const int*   ei   = (const int*)d_in[1];
    const int*   batch= (const int*)d_in[2];
    const float* W1   = (const float*)d_in[3];
    const float* b1   = (const float*)d_in[4];
    const float* W2   = (const float*)d_in[5];
    const float* b2   = (const float*)d_in[6];
    const float* W3   = (const float*)d_in[7];
    const float* b3   = (const float*)d_in[8];
    const float* Wfc  = (const float*)d_in[9];
    const float* bfc  = (const float*)d_in[10];
    float* out = (float*)d_out;

    const int N = in_sizes[2];
    const int E = in_sizes[1] / 2;
    const int G = out_size / 11;
    const int* src = ei;
    const int* dst = ei + E;

    // workspace layout (f32):
    //   agg1[N*9] | h1[N*64] | agg2[N*64] | h2[N*128]
    //   t3/h3 reuses h1's slot; agg3 reuses agg2's slot.
    float* ws   = (float*)d_ws;
    float* agg1 = ws;
    float* h1   = agg1 + (size_t)N * 9;
    float* agg2 = h1 + (size_t)N * 64;
    float* h2   = agg2 + (size_t)N * 64;
    float* t3   = h1;    // free after layer-2 linear
    float* agg3 = agg2;  // free after layer-2 linear

    hipMemsetAsync(agg1, 0, (size_t)N * 9 * sizeof(float), stream);
    hipMemsetAsync(agg2, 0, (size_t)N * 64 * sizeof(float), stream);

    // Layer 1: aggregate in 9-dim input space, then Linear 9->64 + relu
    scatter9_kernel<<<(E + 255) / 256, 256, 0, stream>>>(x, src, dst, agg1, E);
    node1_kernel<<<(N * 64 + 255) / 256, 256, 0, stream>>>(x, agg1, W1, b1, h1, N);

    // Layer 2: aggregate h1 (64-dim), then Linear 64->128 + relu
    scatter_kernel<64><<<(E * 16 + 255) / 256, 256, 0, stream>>>(h1, src, dst, agg2, E);
    linear_kernel<64, 128, 32, true><<<(N + 31) / 32, 256, 0, stream>>>(h1, agg2, W2, b2, h2, N);

    // Layer 3: transform FIRST (128->64), aggregate t3 (64-dim), then +b3, relu
    hipMemsetAsync(agg3, 0, (size_t)N * 64 * sizeof(float), stream);
    linear_kernel<128, 64, 32, false><<<(N + 31) / 32, 256, 0, stream>>>(h2, nullptr, W3, nullptr, t3, N);
    scatter_kernel<64><<<(E * 16 + 255) / 256, 256, 0, stream>>>(t3, src, dst, agg3, E);
    node3_kernel<<<(N * 16 + 255) / 256, 256, 0, stream>>>(t3, agg3, b3, N * 16);

    // Mean pool (batch sorted -> binary search, no atomics) + FC 64->11
    pool_fc_kernel<<<G, 64, 0, stream>>>(t3, batch, Wfc, bfc, out, N);
}

// Round 2
// 605.895 us; speedup vs baseline: 5.8752x; 5.8752x over previous
//
#include <hip/hip_runtime.h>
#include <hip/hip_bf16.h>

// ---------------------------------------------------------------------------
// GIN (3 layers, eps=0) + global mean pool + FC — CSR-gather formulation.
//
// Round-1 lesson: f32 global atomics write through past L2 (non-coherent
// per-XCD L2s) -> 1.64 GB HBM write traffic per 64-dim scatter (16 B per
// atomic). Replace scatter+atomics with device-built CSR (by dst) + per-node
// gather: coalesced 256 B row reads from an L2/L3-resident table.
//
// Pipeline (all on `stream`):
//   build CSR: deg histogram -> exclusive scan -> cursor fill
//   L1: fused gather(9-dim) + Linear 9->64 + relu          (wave per node)
//   L2: gather64 (self+edges) -> Linear 64->128 + relu
//   L3: Linear 128->64 first, gather64 (+b3, relu) fused
//   mean-pool per graph (batch sorted -> binary search) + FC 64->11
// ---------------------------------------------------------------------------

#define SCAN_BS 512

__global__ __launch_bounds__(256) void hist_kernel(
    const int* __restrict__ dst, int* __restrict__ deg, int E)
{
    int e = blockIdx.x * 256 + threadIdx.x;
    if (e < E) atomicAdd(&deg[dst[e]], 1);
}

__global__ __launch_bounds__(SCAN_BS) void scan_k1(
    const int* __restrict__ deg, int* __restrict__ rs,
    int* __restrict__ bsum, int N)
{
    __shared__ int tmp[SCAN_BS];
    int i = blockIdx.x * SCAN_BS + threadIdx.x;
    int v = (i < N) ? deg[i] : 0;
    tmp[threadIdx.x] = v;
    __syncthreads();
    for (int off = 1; off < SCAN_BS; off <<= 1) {
        int t = (threadIdx.x >= off) ? tmp[threadIdx.x - off] : 0;
        __syncthreads();
        tmp[threadIdx.x] += t;
        __syncthreads();
    }
    if (i < N) rs[i + 1] = tmp[threadIdx.x];
    if (threadIdx.x == SCAN_BS - 1) bsum[blockIdx.x] = tmp[threadIdx.x];
}

__global__ __launch_bounds__(1024) void scan_k2(int* __restrict__ bsum, int B)
{
    __shared__ int tmp[1024];
    int v = (threadIdx.x < B) ? bsum[threadIdx.x] : 0;
    tmp[threadIdx.x] = v;
    __syncthreads();
    for (int off = 1; off < 1024; off <<= 1) {
        int t = (threadIdx.x >= off) ? tmp[threadIdx.x - off] : 0;
        __syncthreads();
        tmp[threadIdx.x] += t;
        __syncthreads();
    }
    if (threadIdx.x < B) bsum[threadIdx.x] = tmp[threadIdx.x] - v; // exclusive
}

__global__ __launch_bounds__(SCAN_BS) void scan_k3(
    int* __restrict__ rs, const int* __restrict__ bsum, int N)
{
    int i = blockIdx.x * SCAN_BS + threadIdx.x;
    if (i < N) rs[i + 1] += bsum[blockIdx.x];
    if (blockIdx.x == 0 && threadIdx.x == 0) rs[0] = 0;
}

__global__ __launch_bounds__(256) void fill_kernel(
    const int* __restrict__ src, const int* __restrict__ dst,
    int* __restrict__ cursor, int* __restrict__ eidx, int E)
{
    int e = blockIdx.x * 256 + threadIdx.x;
    if (e < E) {
        int pos = atomicAdd(&cursor[dst[e]], 1);
        eidx[pos] = src[e];
    }
}

// Fused layer 1: per node, 9-dim gather over in-edges (+self), then
// Linear 9->64 + relu. One wave (64 lanes) per node, 4 nodes/block.
__global__ __launch_bounds__(256) void node1_fused_kernel(
    const float* __restrict__ x, const int* __restrict__ rs,
    const int* __restrict__ eidx, const float* __restrict__ W1,
    const float* __restrict__ b1, float* __restrict__ h1, int N)
{
    __shared__ float Wl[576];
    __shared__ float bl[64];
    for (int i = threadIdx.x; i < 576; i += 256) Wl[i] = W1[i];
    if (threadIdx.x < 64) bl[threadIdx.x] = b1[threadIdx.x];
    __syncthreads();
    int n = blockIdx.x * 4 + (threadIdx.x >> 6);
    int lane = threadIdx.x & 63;
    if (n >= N) return;
    int e0 = rs[n], e1 = rs[n + 1];
    float a[9];
    #pragma unroll
    for (int k = 0; k < 9; ++k) a[k] = 0.f;
    for (int e = e0 + lane; e < e1; e += 64) {
        const float* xr = &x[(size_t)eidx[e] * 9];
        #pragma unroll
        for (int k = 0; k < 9; ++k) a[k] += xr[k];
    }
    if (lane == 0) {
        const float* xr = &x[(size_t)n * 9];
        #pragma unroll
        for (int k = 0; k < 9; ++k) a[k] += xr[k];
    }
    // butterfly: every lane ends with the node total
    #pragma unroll
    for (int m = 32; m > 0; m >>= 1) {
        #pragma unroll
        for (int k = 0; k < 9; ++k) a[k] += __shfl_xor(a[k], m);
    }
    // lane o computes output o
    float s = bl[lane];
    const float* wr = &Wl[lane * 9];
    #pragma unroll
    for (int k = 0; k < 9; ++k) s += a[k] * wr[k];
    h1[(size_t)n * 64 + lane] = fmaxf(s, 0.f);
}

// 64-dim gather: out[n] = feat[n] + sum_{e in CSR[n]} feat[eidx[e]]
// (optionally + bias, relu). One wave per node, lane = dim.
template<bool BIAS_RELU>
__global__ __launch_bounds__(256) void gather64_kernel(
    const float* __restrict__ feat, const int* __restrict__ rs,
    const int* __restrict__ eidx, const float* __restrict__ bias,
    float* __restrict__ out, int N)
{
    int n = blockIdx.x * 4 + (threadIdx.x >> 6);
    if (n >= N) return;
    int lane = threadIdx.x & 63;
    float acc = feat[(size_t)n * 64 + lane];
    int e0 = rs[n], e1 = rs[n + 1];
    int e = e0;
    for (; e + 2 <= e1; e += 2) {
        int s0 = eidx[e], s1 = eidx[e + 1];
        acc += feat[(size_t)s0 * 64 + lane];
        acc += feat[(size_t)s1 * 64 + lane];
    }
    if (e < e1) acc += feat[(size_t)eidx[e] * 64 + lane];
    if (BIAS_RELU) acc = fmaxf(acc + bias[lane], 0.f);
    out[(size_t)n * 64 + lane] = acc;
}

// Y[n,:OUT] = A[n] @ W^T (+bias) (relu optional). W is [OUT,IN] row-major.
template<int IN, int OUT, int NB, bool RELU>
__global__ __launch_bounds__(256) void linear_kernel(
    const float* __restrict__ A, const float* __restrict__ W,
    const float* __restrict__ bias, float* __restrict__ Y, int N)
{
    constexpr int INP = IN + 4;
    constexpr int OT  = OUT / 4;
    constexpr int NPT = (NB * OT) / 256;
    __shared__ float Wl[IN][OUT];   // W transposed: [k][o]
    __shared__ float S[NB][INP];
    int tid = threadIdx.x;
    for (int i = tid; i < IN * OUT; i += 256) {
        int k = i / OUT, o = i % OUT;
        Wl[k][o] = W[o * IN + k];
    }
    int n0 = blockIdx.x * NB;
    for (int i = tid; i < NB * IN / 4; i += 256) {
        int idx = i * 4;
        int node = idx / IN, k = idx % IN;
        int gn = n0 + node;
        float4 v = make_float4(0.f, 0.f, 0.f, 0.f);
        if (gn < N) v = *(const float4*)&A[(size_t)gn * IN + k];
        *(float4*)&S[node][k] = v;
    }
    __syncthreads();
    int ot = (tid % OT) * 4;
    int nt = (tid / OT) * NPT;
    float acc[NPT][4];
    #pragma unroll
    for (int i = 0; i < NPT; ++i)
        acc[i][0] = acc[i][1] = acc[i][2] = acc[i][3] = 0.f;
    #pragma unroll 4
    for (int k = 0; k < IN; ++k) {
        float4 w = *(const float4*)&Wl[k][ot];
        #pragma unroll
        for (int i = 0; i < NPT; ++i) {
            float a = S[nt + i][k];
            acc[i][0] += a * w.x; acc[i][1] += a * w.y;
            acc[i][2] += a * w.z; acc[i][3] += a * w.w;
        }
    }
    float4 bv = make_float4(0.f, 0.f, 0.f, 0.f);
    if (bias) bv = *(const float4*)&bias[ot];
    #pragma unroll
    for (int i = 0; i < NPT; ++i) {
        int gn = n0 + nt + i;
        if (gn < N) {
            float4 r;
            r.x = acc[i][0] + bv.x; r.y = acc[i][1] + bv.y;
            r.z = acc[i][2] + bv.z; r.w = acc[i][3] + bv.w;
            if (RELU) {
                r.x = fmaxf(r.x, 0.f); r.y = fmaxf(r.y, 0.f);
                r.z = fmaxf(r.z, 0.f); r.w = fmaxf(r.w, 0.f);
            }
            *(float4*)&Y[(size_t)gn * OUT + ot] = r;
        }
    }
}

__device__ inline int lower_bound_i(const int* a, int n, int v) {
    int lo = 0, hi = n;
    while (lo < hi) {
        int mid = (lo + hi) >> 1;
        if (a[mid] < v) lo = mid + 1; else hi = mid;
    }
    return lo;
}

// One block (4 waves) per graph: mean-pool node range + FC 64->11.
__global__ __launch_bounds__(256) void pool_fc_kernel(
    const float* __restrict__ h3, const int* __restrict__ batch,
    const float* __restrict__ Wfc, const float* __restrict__ bfc,
    float* __restrict__ out, int N)
{
    int g = blockIdx.x;
    int tid = threadIdx.x;
    int w = tid >> 6, lane = tid & 63;
    int lo = lower_bound_i(batch, N, g);
    int hi = lower_bound_i(batch, N, g + 1);
    float sum = 0.f;
    for (int i = lo + w; i < hi; i += 4) sum += h3[(size_t)i * 64 + lane];
    __shared__ float P[4][64];
    P[w][lane] = sum;
    __syncthreads();
    if (w == 0) {
        float s = P[0][lane] + P[1][lane] + P[2][lane] + P[3][lane];
        float cnt = (float)((hi - lo) > 0 ? (hi - lo) : 1);
        P[0][lane] = s / cnt;
    }
    __syncthreads();
    if (tid < 11) {
        float s = bfc[tid];
        const float* wr = &Wfc[tid * 64];
        #pragma unroll 8
        for (int k = 0; k < 64; ++k) s += P[0][k] * wr[k];
        out[g * 11 + tid] = s;
    }
}

extern "C" void kernel_launch(void* const* d_in, const int* in_sizes, int n_in,
                              void* d_out, int out_size, void* d_ws, size_t ws_size,
                              hipStream_t stream) {
    const float* x    = (const float*)d_in[0];
    const int*   ei   = (const int*)d_in[1];
    const int*   batch= (const int*)d_in[2];
    const float* W1   = (const float*)d_in[3];
    const float* b1   = (const float*)d_in[4];
    const float* W2   = (const float*)d_in[5];
    const float* b2   = (const float*)d_in[6];
    const float* W3   = (const float*)d_in[7];
    const float* b3   = (const float*)d_in[8];
    const float* Wfc  = (const float*)d_in[9];
    const float* bfc  = (const float*)d_in[10];
    float* out = (float*)d_out;

    const int N = in_sizes[2];
    const int E = in_sizes[1] / 2;
    const int G = out_size / 11;
    const int* src = ei;
    const int* dst = ei + E;

    // workspace layout:
    //   A: 128N f32  (holds: deg/cursor ints during build -> h1 -> h2 -> h3)
    //   B: 64N  f32  (holds: buf2 -> t3)
    //   rowstart: (N+1) i32 | eidx: E i32 | bsum: 1024 i32
    float* A = (float*)d_ws;
    float* B = A + (size_t)128 * N;
    int* rowstart = (int*)(B + (size_t)64 * N);
    int* eidx = rowstart + (N + 1);
    int* bsum = eidx + E;

    int* deg    = (int*)A;          // dead before h1 is written
    int* cursor = (int*)A + N;      // dead before h1 is written
    float* h1   = A;                // 64N
    float* buf2 = B;                // 64N: h1 + agg (self included)
    float* h2   = A;                // 128N (h1 dead by then)
    float* t3   = B;                // 64N (buf2 dead by then)
    float* h3   = A;                // 64N (h2 dead by then)

    const int SB = (N + SCAN_BS - 1) / SCAN_BS;

    // ---- build CSR (by dst) ----
    hipMemsetAsync(deg, 0, (size_t)N * sizeof(int), stream);
    hist_kernel<<<(E + 255) / 256, 256, 0, stream>>>(dst, deg, E);
    scan_k1<<<SB, SCAN_BS, 0, stream>>>(deg, rowstart, bsum, N);
    scan_k2<<<1, 1024, 0, stream>>>(bsum, SB);
    scan_k3<<<SB, SCAN_BS, 0, stream>>>(rowstart, bsum, N);
    hipMemcpyAsync(cursor, rowstart, (size_t)N * sizeof(int),
                   hipMemcpyDeviceToDevice, stream);
    fill_kernel<<<(E + 255) / 256, 256, 0, stream>>>(src, dst, cursor, eidx, E);

    // ---- layer 1 (fused gather9 + Linear 9->64 + relu) ----
    node1_fused_kernel<<<(N + 3) / 4, 256, 0, stream>>>(
        x, rowstart, eidx, W1, b1, h1, N);

    // ---- layer 2: gather64 then Linear 64->128 + relu ----
    gather64_kernel<false><<<(N + 3) / 4, 256, 0, stream>>>(
        h1, rowstart, eidx, nullptr, buf2, N);
    linear_kernel<64, 128, 32, true><<<(N + 31) / 32, 256, 0, stream>>>(
        buf2, W2, b2, h2, N);

    // ---- layer 3: Linear 128->64 first, then gather64 (+b3, relu) ----
    linear_kernel<128, 64, 32, false><<<(N + 31) / 32, 256, 0, stream>>>(
        h2, W3, nullptr, t3, N);
    gather64_kernel<true><<<(N + 3) / 4, 256, 0, stream>>>(
        t3, rowstart, eidx, b3, h3, N);

    // ---- mean pool + FC ----
    pool_fc_kernel<<<G, 256, 0, stream>>>(h3, batch, Wfc, bfc, out, N);
}